// Round 1
// baseline (3774.588 us; speedup 1.0000x reference)
//
#include <hip/hip_runtime.h>
#include <hip/hip_fp16.h>
#include <hip/hip_cooperative_groups.h>

namespace cg = cooperative_groups;

#define N_NODES 50000
#define N_EDGES 1600000
#define T_STEPS 50
#define DT      0.02f
#define NB      256    // buckets
#define NPB     196    // nodes per bucket (196*256 >= 50000)
#define CAP     6912   // max edges per bucket (mean 6272, +8 sigma)
#define TILE    4096   // edges per bucket_kernel block
#define G       8      // lanes per node group in step phase
#define NBLK    512    // persistent blocks (2/CU, co-resident)
#define NTILES  1563   // ceil(50000 / 32) node tiles of 32
#define LCAP    5120   // LDS edge records per block (4 tiles mean 4096, +16 sigma)

// ---------------- setup ----------------

__global__ __launch_bounds__(256) void zero_kernel(int* __restrict__ bucket_count) {
    bucket_count[threadIdx.x] = 0;
}

// ---------------- bucketing: staged, line-friendly appends ----------------
// u64 item: low 32 = record (src | fp16w<<16), high 32 = target-within-bucket
__global__ __launch_bounds__(256) void bucket_kernel(
    const int* __restrict__ src, const int* __restrict__ tgt,
    const float* __restrict__ sign, const float* __restrict__ syn_count,
    const float* __restrict__ syn_strength,
    int* __restrict__ bucket_count, unsigned long long* __restrict__ rec_buf)
{
    __shared__ int hist[NB], base_s[NB], cur[NB];
    int tid = threadIdx.x;
    hist[tid] = 0;
    __syncthreads();

    int e0 = blockIdx.x * TILE + tid;
    int bkt[16];
    unsigned long long item[16];
#pragma unroll
    for (int k = 0; k < 16; ++k) {
        int e = e0 + k * 256;
        if (e < N_EDGES) {
            int t = tgt[e];
            int b = t / NPB;
            int tl = t - b * NPB;
            float w = sign[e] * fmaxf(syn_count[e], 0.f) * fmaxf(syn_strength[e], 0.f);
            unsigned int rec = (unsigned int)src[e] |
                               ((unsigned int)__half_as_ushort(__float2half(w)) << 16);
            bkt[k] = b;
            item[k] = (unsigned long long)rec | ((unsigned long long)tl << 32);
            atomicAdd(&hist[b], 1);
        } else {
            bkt[k] = -1;
        }
    }
    __syncthreads();
    base_s[tid] = atomicAdd(&bucket_count[tid], hist[tid]);
    cur[tid] = 0;
    __syncthreads();
#pragma unroll
    for (int k = 0; k < 16; ++k) {
        if (bkt[k] >= 0) {
            int p = base_s[bkt[k]] + atomicAdd(&cur[bkt[k]], 1);
            if (p < CAP) rec_buf[(size_t)bkt[k] * CAP + p] = item[k];
        }
    }
}

// ---------------- per-bucket counting sort -> global CSR ----------------
__global__ __launch_bounds__(256) void sort_kernel(
    const int* __restrict__ bucket_count,
    const unsigned long long* __restrict__ rec_buf,
    unsigned int* __restrict__ edges_g, int* __restrict__ offsets)
{
    __shared__ unsigned int sorted[CAP];          // 27.6 KB
    __shared__ int cnts[NB];
    __shared__ int loc_off[NPB + 1];
    __shared__ int loc_cur[NPB];

    int b = blockIdx.x;
    int tid = threadIdx.x;
    int node_base = b * NPB;
    int n_nodes = min(NPB, N_NODES - node_base);

    cnts[tid] = min(bucket_count[tid], CAP);
    if (tid < NPB) loc_cur[tid] = 0;
    __syncthreads();

    __shared__ int ebase_s;
    if (tid == 0) {
        int r = 0;
        for (int i = 0; i < b; ++i) r += cnts[i];
        ebase_s = r;
    }
    __syncthreads();
    int ebase = ebase_s;
    int cnt = cnts[b];

    // pass 1: histogram by local target
    for (int i = tid; i < cnt; i += 256) {
        unsigned long long it = rec_buf[(size_t)b * CAP + i];
        atomicAdd(&loc_cur[(int)(it >> 32)], 1);
    }
    __syncthreads();
    if (tid == 0) {
        int r = 0;
        for (int n = 0; n < n_nodes; ++n) { loc_off[n] = r; r += loc_cur[n]; }
        loc_off[n_nodes] = r;
    }
    __syncthreads();
    if (tid < n_nodes) loc_cur[tid] = loc_off[tid];
    __syncthreads();

    // pass 2: place (rec_buf re-read is L2-hot)
    for (int i = tid; i < cnt; i += 256) {
        unsigned long long it = rec_buf[(size_t)b * CAP + i];
        int p = atomicAdd(&loc_cur[(int)(it >> 32)], 1);
        sorted[p] = (unsigned int)it;
    }
    __syncthreads();

    // coalesced CSR write + offsets
    for (int i = tid; i < cnt; i += 256) edges_g[ebase + i] = sorted[i];
    for (int n = tid; n < n_nodes; n += 256) offsets[node_base + n] = ebase + loc_off[n];
    if (b == NB - 1 && tid == 0) offsets[N_NODES] = ebase + cnt;
}

// ---------------- persistent all-steps kernel ----------------
// One cooperative launch runs all 50 steps. Each block owns 3-4 tiles of 32
// nodes; their edge records are staged in LDS ONCE; v/alpha/bias/CSR ranges
// live in registers for the whole simulation. grid.sync() between steps.
// Edge ordering, G=8 shuffle reduce, fp16 weights identical to the previous
// passing kernel -> bit-identical numerics.

__device__ __forceinline__ float rec_w(unsigned int rec) {
    return __half2float(__ushort_as_half((unsigned short)(rec >> 16)));
}

__global__ __launch_bounds__(256, 2) void persist_kernel(
    float* rates_a, float* rates_b,                    // [N][4] each
    const float* __restrict__ bias, const float* __restrict__ time_const,
    const int* __restrict__ offsets, const unsigned int* __restrict__ edges,
    const float* __restrict__ x, float* __restrict__ out)
{
    __shared__ unsigned int eL[LCAP];                  // 20 KB
    cg::grid_group grid = cg::this_grid();

    const int b    = blockIdx.x;
    const int tid  = threadIdx.x;
    const int lane = tid & (G - 1);
    const int grp  = tid / G;                          // 0..31 node-in-tile
    const int nslot = 3 + (b < (NTILES - 3 * NBLK));   // blocks 0..26 own 4 tiles

    int   lbeg_r[4], lend_r[4], node_r[4];
    float v_r[4], al_r[4], bi_r[4];
#pragma unroll
    for (int k = 0; k < 4; ++k) {
        lbeg_r[k] = 0; lend_r[k] = 0; node_r[k] = -1;
        v_r[k] = 0.f; al_r[k] = 0.f; bi_r[k] = 0.f;
    }

    // ---- staging: edges -> LDS, per-node state -> registers, rates(t=0) ----
    int lbase = 0;
#pragma unroll
    for (int k = 0; k < 4; ++k) {
        if (k < nslot) {
            const int tt    = b + k * NBLK;
            const int node0 = tt * 32;
            const int ncnt  = min(32, N_NODES - node0);
            const int gbeg  = offsets[node0];
            const int gend  = offsets[node0 + ncnt];
            int cnt = gend - gbeg;
            if (lbase + cnt > LCAP) cnt = LCAP - lbase;   // safety, never expected
            for (int i = tid; i < cnt; i += 256) eL[lbase + i] = edges[gbeg + i];
            if (grp < ncnt) {
                const int node = node0 + grp;
                node_r[k] = node;
                int ob = min(offsets[node] - gbeg, cnt);
                int oe = min(offsets[node + 1] - gbeg, cnt);
                lbeg_r[k] = lbase + ob;
                lend_r[k] = lbase + oe;
                const float bb = bias[node];
                bi_r[k] = bb;
                al_r[k] = DT / fmaxf(time_const[node], DT);
                v_r[k]  = bb;
                if (lane < 4) rates_a[node * 4 + lane] = fmaxf(bb, 0.f);
            }
            lbase += cnt;
        }
    }
    __syncthreads();
    grid.sync();   // rates(t=0) visible device-wide

    const int TN = T_STEPS * N_NODES;
    for (int t = 0; t < T_STEPS; ++t) {
        const float4* rin  = (const float4*)((t & 1) ? rates_b : rates_a);
        float*        rout = (t & 1) ? rates_a : rates_b;

#pragma unroll
        for (int k = 0; k < 4; ++k) {
            if (k < nslot) {
                const int node = node_r[k];
                const int oi = lane * TN + t * N_NODES + node;
                float xv = 0.f;
                if (node >= 0 && lane < 4) xv = x[oi];   // issue early, hides under gathers

                float4 acc = make_float4(0.f, 0.f, 0.f, 0.f);
                const int end = lend_r[k];
                int i = lbeg_r[k] + lane;
                unsigned int r0 = (i          < end) ? eL[i]         : 0u;
                unsigned int r1 = (i + G      < end) ? eL[i + G]     : 0u;
                unsigned int r2 = (i + 2 * G  < end) ? eL[i + 2 * G] : 0u;
                unsigned int r3 = (i + 3 * G  < end) ? eL[i + 3 * G] : 0u;
                while (i < end) {
                    unsigned int n0 = (i + 4 * G < end) ? eL[i + 4 * G] : 0u;
                    unsigned int n1 = (i + 5 * G < end) ? eL[i + 5 * G] : 0u;
                    unsigned int n2 = (i + 6 * G < end) ? eL[i + 6 * G] : 0u;
                    unsigned int n3 = (i + 7 * G < end) ? eL[i + 7 * G] : 0u;
                    float4 a0 = rin[r0 & 0xFFFFu];
                    float4 a1 = rin[r1 & 0xFFFFu];
                    float4 a2 = rin[r2 & 0xFFFFu];
                    float4 a3 = rin[r3 & 0xFFFFu];
                    float w0 = rec_w(r0), w1 = rec_w(r1), w2 = rec_w(r2), w3 = rec_w(r3);
                    acc.x = fmaf(a0.x, w0, acc.x); acc.y = fmaf(a0.y, w0, acc.y);
                    acc.z = fmaf(a0.z, w0, acc.z); acc.w = fmaf(a0.w, w0, acc.w);
                    acc.x = fmaf(a1.x, w1, acc.x); acc.y = fmaf(a1.y, w1, acc.y);
                    acc.z = fmaf(a1.z, w1, acc.z); acc.w = fmaf(a1.w, w1, acc.w);
                    acc.x = fmaf(a2.x, w2, acc.x); acc.y = fmaf(a2.y, w2, acc.y);
                    acc.z = fmaf(a2.z, w2, acc.z); acc.w = fmaf(a2.w, w2, acc.w);
                    acc.x = fmaf(a3.x, w3, acc.x); acc.y = fmaf(a3.y, w3, acc.y);
                    acc.z = fmaf(a3.z, w3, acc.z); acc.w = fmaf(a3.w, w3, acc.w);
                    r0 = n0; r1 = n1; r2 = n2; r3 = n3;
                    i += 4 * G;
                }

#pragma unroll
                for (int m = 1; m < G; m <<= 1) {
                    acc.x += __shfl_xor(acc.x, m, 64);
                    acc.y += __shfl_xor(acc.y, m, 64);
                    acc.z += __shfl_xor(acc.z, m, 64);
                    acc.w += __shfl_xor(acc.w, m, 64);
                }

                if (node >= 0 && lane < 4) {
                    float sum = (lane == 0) ? acc.x : (lane == 1) ? acc.y
                              : (lane == 2) ? acc.z : acc.w;
                    float vv = v_r[k];
                    float vn = vv + al_r[k] * (bi_r[k] + sum + xv - vv);
                    v_r[k] = vn;
                    float r = fmaxf(vn, 0.f);
                    rout[node * 4 + lane] = r;
                    out[oi] = r;
                }
            }
        }
        if (t < T_STEPS - 1) grid.sync();   // rates(t+1) consumed next step
    }
}

// ---------------- launch ----------------

extern "C" void kernel_launch(void* const* d_in, const int* in_sizes, int n_in,
                              void* d_out, int out_size, void* d_ws, size_t ws_size,
                              hipStream_t stream) {
    const float* x            = (const float*)d_in[0];
    const float* bias         = (const float*)d_in[1];
    const float* time_const   = (const float*)d_in[2];
    const float* sign         = (const float*)d_in[3];
    const float* syn_count    = (const float*)d_in[4];
    const float* syn_strength = (const float*)d_in[5];
    const int*   src_idx      = (const int*)d_in[6];
    const int*   tgt_idx      = (const int*)d_in[7];
    float* out = (float*)d_out;

    char* ws = (char*)d_ws;
    size_t off = 0;
    auto alloc = [&](size_t bytes) -> void* {
        void* p = ws + off;
        off = (off + bytes + 255) & ~(size_t)255;
        return p;
    };
    float* rates_a  = (float*)alloc((size_t)N_NODES * 16);
    float* rates_b  = (float*)alloc((size_t)N_NODES * 16);
    int*   offsets  = (int*)  alloc((size_t)(N_NODES + 1) * 4);
    int*   bucket_count = (int*)alloc((size_t)NB * 4);
    unsigned int* edges = (unsigned int*)alloc((size_t)N_EDGES * 4);
    unsigned long long* rec_buf =
        (unsigned long long*)alloc((size_t)NB * CAP * 8);   // 14.2 MB

    int nb_tiles = (N_EDGES + TILE - 1) / TILE;

    zero_kernel<<<1, 256, 0, stream>>>(bucket_count);
    bucket_kernel<<<nb_tiles, 256, 0, stream>>>(src_idx, tgt_idx, sign, syn_count,
                                                syn_strength, bucket_count, rec_buf);
    sort_kernel<<<NB, 256, 0, stream>>>(bucket_count, rec_buf, edges, offsets);

    void* kargs[] = {
        (void*)&rates_a, (void*)&rates_b, (void*)&bias, (void*)&time_const,
        (void*)&offsets, (void*)&edges, (void*)&x, (void*)&out
    };
    hipLaunchCooperativeKernel((const void*)persist_kernel, dim3(NBLK), dim3(256),
                               kargs, 0, stream);
}

// Round 2
// 2805.708 us; speedup vs baseline: 1.3453x; 1.3453x over previous
//
#include <hip/hip_runtime.h>
#include <hip/hip_fp16.h>

#define N_NODES 50000
#define N_EDGES 1600000
#define T_STEPS 50
#define DT      0.02f
#define NB      256    // buckets
#define NPB     196    // nodes per bucket (196*256 >= 50000)
#define CAP     6912   // max edges per bucket (mean 6272, +8 sigma)
#define TILE    4096   // edges per bucket_kernel block
#define G       8      // lanes per node group in step phase
#define NBLK    512    // persistent blocks (2/CU, co-resident)
#define NTILES  1563   // ceil(50000 / 32) node tiles of 32
#define LCAP    5120   // LDS edge records per block (4 tiles mean 4096, +16 sigma)

// ---------------- setup ----------------

__global__ __launch_bounds__(256) void zero_kernel(int* __restrict__ bucket_count,
                                                   unsigned int* __restrict__ bar) {
    bucket_count[threadIdx.x] = 0;
    if (threadIdx.x == 0) *bar = 0u;
}

// ---------------- bucketing: staged, line-friendly appends ----------------
// u64 item: low 32 = record (src | fp16w<<16), high 32 = target-within-bucket
__global__ __launch_bounds__(256) void bucket_kernel(
    const int* __restrict__ src, const int* __restrict__ tgt,
    const float* __restrict__ sign, const float* __restrict__ syn_count,
    const float* __restrict__ syn_strength,
    int* __restrict__ bucket_count, unsigned long long* __restrict__ rec_buf)
{
    __shared__ int hist[NB], base_s[NB], cur[NB];
    int tid = threadIdx.x;
    hist[tid] = 0;
    __syncthreads();

    int e0 = blockIdx.x * TILE + tid;
    int bkt[16];
    unsigned long long item[16];
#pragma unroll
    for (int k = 0; k < 16; ++k) {
        int e = e0 + k * 256;
        if (e < N_EDGES) {
            int t = tgt[e];
            int b = t / NPB;
            int tl = t - b * NPB;
            float w = sign[e] * fmaxf(syn_count[e], 0.f) * fmaxf(syn_strength[e], 0.f);
            unsigned int rec = (unsigned int)src[e] |
                               ((unsigned int)__half_as_ushort(__float2half(w)) << 16);
            bkt[k] = b;
            item[k] = (unsigned long long)rec | ((unsigned long long)tl << 32);
            atomicAdd(&hist[b], 1);
        } else {
            bkt[k] = -1;
        }
    }
    __syncthreads();
    base_s[tid] = atomicAdd(&bucket_count[tid], hist[tid]);
    cur[tid] = 0;
    __syncthreads();
#pragma unroll
    for (int k = 0; k < 16; ++k) {
        if (bkt[k] >= 0) {
            int p = base_s[bkt[k]] + atomicAdd(&cur[bkt[k]], 1);
            if (p < CAP) rec_buf[(size_t)bkt[k] * CAP + p] = item[k];
        }
    }
}

// ---------------- per-bucket counting sort -> global CSR ----------------
__global__ __launch_bounds__(256) void sort_kernel(
    const int* __restrict__ bucket_count,
    const unsigned long long* __restrict__ rec_buf,
    unsigned int* __restrict__ edges_g, int* __restrict__ offsets)
{
    __shared__ unsigned int sorted[CAP];          // 27.6 KB
    __shared__ int cnts[NB];
    __shared__ int loc_off[NPB + 1];
    __shared__ int loc_cur[NPB];

    int b = blockIdx.x;
    int tid = threadIdx.x;
    int node_base = b * NPB;
    int n_nodes = min(NPB, N_NODES - node_base);

    cnts[tid] = min(bucket_count[tid], CAP);
    if (tid < NPB) loc_cur[tid] = 0;
    __syncthreads();

    __shared__ int ebase_s;
    if (tid == 0) {
        int r = 0;
        for (int i = 0; i < b; ++i) r += cnts[i];
        ebase_s = r;
    }
    __syncthreads();
    int ebase = ebase_s;
    int cnt = cnts[b];

    // pass 1: histogram by local target
    for (int i = tid; i < cnt; i += 256) {
        unsigned long long it = rec_buf[(size_t)b * CAP + i];
        atomicAdd(&loc_cur[(int)(it >> 32)], 1);
    }
    __syncthreads();
    if (tid == 0) {
        int r = 0;
        for (int n = 0; n < n_nodes; ++n) { loc_off[n] = r; r += loc_cur[n]; }
        loc_off[n_nodes] = r;
    }
    __syncthreads();
    if (tid < n_nodes) loc_cur[tid] = loc_off[tid];
    __syncthreads();

    // pass 2: place (rec_buf re-read is L2-hot)
    for (int i = tid; i < cnt; i += 256) {
        unsigned long long it = rec_buf[(size_t)b * CAP + i];
        int p = atomicAdd(&loc_cur[(int)(it >> 32)], 1);
        sorted[p] = (unsigned int)it;
    }
    __syncthreads();

    // coalesced CSR write + offsets
    for (int i = tid; i < cnt; i += 256) edges_g[ebase + i] = sorted[i];
    for (int n = tid; n < n_nodes; n += 256) offsets[node_base + n] = ebase + loc_off[n];
    if (b == NB - 1 && tid == 0) offsets[N_NODES] = ebase + cnt;
}

// ---------------- lightweight grid barrier ----------------
// Only thread 0 of each block touches the counter: release-RMW publishes the
// block's rates stores (L2 writeback), relaxed polls with s_sleep backoff,
// one acquire fence (L1+L2 invalidate) makes peers' stores visible, then
// __syncthreads propagates within the block. Counter is monotonic across
// barriers; target = phase * NBLK.
__device__ __forceinline__ void grid_barrier(unsigned int* cnt, unsigned int target) {
    __syncthreads();
    if (threadIdx.x == 0) {
        __hip_atomic_fetch_add(cnt, 1u, __ATOMIC_RELEASE, __HIP_MEMORY_SCOPE_AGENT);
        while (__hip_atomic_load(cnt, __ATOMIC_RELAXED, __HIP_MEMORY_SCOPE_AGENT) < target)
            __builtin_amdgcn_s_sleep(16);
        __builtin_amdgcn_fence(__ATOMIC_ACQUIRE, "agent");
    }
    __syncthreads();
}

// ---------------- persistent all-steps kernel ----------------
// One cooperative launch runs all 50 steps. Each block owns 3-4 tiles of 32
// nodes; their edge records are staged in LDS ONCE; v/alpha/bias/CSR ranges
// live in registers for the whole simulation. Custom barrier between steps.
// Edge ordering, G=8 shuffle reduce, fp16 weights identical to the passing
// multi-launch kernel -> bit-identical numerics.

__device__ __forceinline__ float rec_w(unsigned int rec) {
    return __half2float(__ushort_as_half((unsigned short)(rec >> 16)));
}

__global__ __launch_bounds__(256, 2) void persist_kernel(
    float* rates_a, float* rates_b,                    // [N][4] each
    const float* __restrict__ bias, const float* __restrict__ time_const,
    const int* __restrict__ offsets, const unsigned int* __restrict__ edges,
    const float* __restrict__ x, float* __restrict__ out,
    unsigned int* __restrict__ bar)
{
    __shared__ unsigned int eL[LCAP];                  // 20 KB
    const int b    = blockIdx.x;
    const int tid  = threadIdx.x;
    const int lane = tid & (G - 1);
    const int grp  = tid / G;                          // 0..31 node-in-tile
    const int nslot = 3 + (b < (NTILES - 3 * NBLK));   // blocks 0..26 own 4 tiles

    int   lbeg_r[4], lend_r[4], node_r[4];
    float v_r[4], al_r[4], bi_r[4];
#pragma unroll
    for (int k = 0; k < 4; ++k) {
        lbeg_r[k] = 0; lend_r[k] = 0; node_r[k] = -1;
        v_r[k] = 0.f; al_r[k] = 0.f; bi_r[k] = 0.f;
    }

    // ---- staging: edges -> LDS, per-node state -> registers, rates(t=0) ----
    int lbase = 0;
#pragma unroll
    for (int k = 0; k < 4; ++k) {
        if (k < nslot) {
            const int tt    = b + k * NBLK;
            const int node0 = tt * 32;
            const int ncnt  = min(32, N_NODES - node0);
            const int gbeg  = offsets[node0];
            const int gend  = offsets[node0 + ncnt];
            int cnt = gend - gbeg;
            if (lbase + cnt > LCAP) cnt = LCAP - lbase;   // safety, never expected
            for (int i = tid; i < cnt; i += 256) eL[lbase + i] = edges[gbeg + i];
            if (grp < ncnt) {
                const int node = node0 + grp;
                node_r[k] = node;
                int ob = min(offsets[node] - gbeg, cnt);
                int oe = min(offsets[node + 1] - gbeg, cnt);
                lbeg_r[k] = lbase + ob;
                lend_r[k] = lbase + oe;
                const float bb = bias[node];
                bi_r[k] = bb;
                al_r[k] = DT / fmaxf(time_const[node], DT);
                v_r[k]  = bb;
                if (lane < 4) rates_a[node * 4 + lane] = fmaxf(bb, 0.f);
            }
            lbase += cnt;
        }
    }
    grid_barrier(bar, NBLK);   // rates(t=0) visible device-wide

    const int TN = T_STEPS * N_NODES;
    for (int t = 0; t < T_STEPS; ++t) {
        const float4* rin  = (const float4*)((t & 1) ? rates_b : rates_a);
        float*        rout = (t & 1) ? rates_a : rates_b;

#pragma unroll
        for (int k = 0; k < 4; ++k) {
            if (k < nslot) {
                const int node = node_r[k];
                const int oi = lane * TN + t * N_NODES + node;
                float xv = 0.f;
                if (node >= 0 && lane < 4) xv = x[oi];   // issue early, hides under gathers

                float4 acc = make_float4(0.f, 0.f, 0.f, 0.f);
                const int end = lend_r[k];
                int i = lbeg_r[k] + lane;
                unsigned int r0 = (i          < end) ? eL[i]         : 0u;
                unsigned int r1 = (i + G      < end) ? eL[i + G]     : 0u;
                unsigned int r2 = (i + 2 * G  < end) ? eL[i + 2 * G] : 0u;
                unsigned int r3 = (i + 3 * G  < end) ? eL[i + 3 * G] : 0u;
                while (i < end) {
                    unsigned int n0 = (i + 4 * G < end) ? eL[i + 4 * G] : 0u;
                    unsigned int n1 = (i + 5 * G < end) ? eL[i + 5 * G] : 0u;
                    unsigned int n2 = (i + 6 * G < end) ? eL[i + 6 * G] : 0u;
                    unsigned int n3 = (i + 7 * G < end) ? eL[i + 7 * G] : 0u;
                    float4 a0 = rin[r0 & 0xFFFFu];
                    float4 a1 = rin[r1 & 0xFFFFu];
                    float4 a2 = rin[r2 & 0xFFFFu];
                    float4 a3 = rin[r3 & 0xFFFFu];
                    float w0 = rec_w(r0), w1 = rec_w(r1), w2 = rec_w(r2), w3 = rec_w(r3);
                    acc.x = fmaf(a0.x, w0, acc.x); acc.y = fmaf(a0.y, w0, acc.y);
                    acc.z = fmaf(a0.z, w0, acc.z); acc.w = fmaf(a0.w, w0, acc.w);
                    acc.x = fmaf(a1.x, w1, acc.x); acc.y = fmaf(a1.y, w1, acc.y);
                    acc.z = fmaf(a1.z, w1, acc.z); acc.w = fmaf(a1.w, w1, acc.w);
                    acc.x = fmaf(a2.x, w2, acc.x); acc.y = fmaf(a2.y, w2, acc.y);
                    acc.z = fmaf(a2.z, w2, acc.z); acc.w = fmaf(a2.w, w2, acc.w);
                    acc.x = fmaf(a3.x, w3, acc.x); acc.y = fmaf(a3.y, w3, acc.y);
                    acc.z = fmaf(a3.z, w3, acc.z); acc.w = fmaf(a3.w, w3, acc.w);
                    r0 = n0; r1 = n1; r2 = n2; r3 = n3;
                    i += 4 * G;
                }

#pragma unroll
                for (int m = 1; m < G; m <<= 1) {
                    acc.x += __shfl_xor(acc.x, m, 64);
                    acc.y += __shfl_xor(acc.y, m, 64);
                    acc.z += __shfl_xor(acc.z, m, 64);
                    acc.w += __shfl_xor(acc.w, m, 64);
                }

                if (node >= 0 && lane < 4) {
                    float sum = (lane == 0) ? acc.x : (lane == 1) ? acc.y
                              : (lane == 2) ? acc.z : acc.w;
                    float vv = v_r[k];
                    float vn = vv + al_r[k] * (bi_r[k] + sum + xv - vv);
                    v_r[k] = vn;
                    float r = fmaxf(vn, 0.f);
                    rout[node * 4 + lane] = r;
                    out[oi] = r;
                }
            }
        }
        if (t < T_STEPS - 1) grid_barrier(bar, (unsigned int)NBLK * (t + 2));
    }
}

// ---------------- launch ----------------

extern "C" void kernel_launch(void* const* d_in, const int* in_sizes, int n_in,
                              void* d_out, int out_size, void* d_ws, size_t ws_size,
                              hipStream_t stream) {
    const float* x            = (const float*)d_in[0];
    const float* bias         = (const float*)d_in[1];
    const float* time_const   = (const float*)d_in[2];
    const float* sign         = (const float*)d_in[3];
    const float* syn_count    = (const float*)d_in[4];
    const float* syn_strength = (const float*)d_in[5];
    const int*   src_idx      = (const int*)d_in[6];
    const int*   tgt_idx      = (const int*)d_in[7];
    float* out = (float*)d_out;

    char* ws = (char*)d_ws;
    size_t off = 0;
    auto alloc = [&](size_t bytes) -> void* {
        void* p = ws + off;
        off = (off + bytes + 255) & ~(size_t)255;
        return p;
    };
    float* rates_a  = (float*)alloc((size_t)N_NODES * 16);
    float* rates_b  = (float*)alloc((size_t)N_NODES * 16);
    int*   offsets  = (int*)  alloc((size_t)(N_NODES + 1) * 4);
    int*   bucket_count = (int*)alloc((size_t)NB * 4);
    unsigned int* bar   = (unsigned int*)alloc(256);
    unsigned int* edges = (unsigned int*)alloc((size_t)N_EDGES * 4);
    unsigned long long* rec_buf =
        (unsigned long long*)alloc((size_t)NB * CAP * 8);   // 14.2 MB

    int nb_tiles = (N_EDGES + TILE - 1) / TILE;

    zero_kernel<<<1, 256, 0, stream>>>(bucket_count, bar);
    bucket_kernel<<<nb_tiles, 256, 0, stream>>>(src_idx, tgt_idx, sign, syn_count,
                                                syn_strength, bucket_count, rec_buf);
    sort_kernel<<<NB, 256, 0, stream>>>(bucket_count, rec_buf, edges, offsets);

    void* kargs[] = {
        (void*)&rates_a, (void*)&rates_b, (void*)&bias, (void*)&time_const,
        (void*)&offsets, (void*)&edges, (void*)&x, (void*)&out, (void*)&bar
    };
    hipLaunchCooperativeKernel((const void*)persist_kernel, dim3(NBLK), dim3(256),
                               kargs, 0, stream);
}

// Round 4
// 2210.340 us; speedup vs baseline: 1.7077x; 1.2694x over previous
//
#include <hip/hip_runtime.h>
#include <hip/hip_fp16.h>

#define N_NODES 50000
#define N_EDGES 1600000
#define T_STEPS 50
#define DT      0.02f
#define NB      256    // buckets
#define NPB     196    // nodes per bucket (196*256 >= 50000)
#define CAP     6912   // max edges per bucket (mean 6272, +8 sigma)
#define TILE    4096   // edges per bucket_kernel block
#define G       8      // lanes per node group in step phase
#define NBLK    512    // persistent blocks (2/CU, co-resident)
#define NTILES  1563   // ceil(50000 / 32) node tiles of 32
#define LCAP    5120   // LDS edge records per block (4 tiles mean 4096, +16 sigma)

typedef __attribute__((ext_vector_type(4))) float f32x4;

// ---------------- setup ----------------

__global__ __launch_bounds__(256) void zero_kernel(int* __restrict__ bucket_count,
                                                   unsigned int* __restrict__ bar) {
    bucket_count[threadIdx.x] = 0;
    if (threadIdx.x < 64) bar[threadIdx.x] = 0u;
}

// ---------------- bucketing: staged, line-friendly appends ----------------
// u64 item: low 32 = record (src | fp16w<<16), high 32 = target-within-bucket
__global__ __launch_bounds__(256) void bucket_kernel(
    const int* __restrict__ src, const int* __restrict__ tgt,
    const float* __restrict__ sign, const float* __restrict__ syn_count,
    const float* __restrict__ syn_strength,
    int* __restrict__ bucket_count, unsigned long long* __restrict__ rec_buf)
{
    __shared__ int hist[NB], base_s[NB], cur[NB];
    int tid = threadIdx.x;
    hist[tid] = 0;
    __syncthreads();

    int e0 = blockIdx.x * TILE + tid;
    int bkt[16];
    unsigned long long item[16];
#pragma unroll
    for (int k = 0; k < 16; ++k) {
        int e = e0 + k * 256;
        if (e < N_EDGES) {
            int t = tgt[e];
            int b = t / NPB;
            int tl = t - b * NPB;
            float w = sign[e] * fmaxf(syn_count[e], 0.f) * fmaxf(syn_strength[e], 0.f);
            unsigned int rec = (unsigned int)src[e] |
                               ((unsigned int)__half_as_ushort(__float2half(w)) << 16);
            bkt[k] = b;
            item[k] = (unsigned long long)rec | ((unsigned long long)tl << 32);
            atomicAdd(&hist[b], 1);
        } else {
            bkt[k] = -1;
        }
    }
    __syncthreads();
    base_s[tid] = atomicAdd(&bucket_count[tid], hist[tid]);
    cur[tid] = 0;
    __syncthreads();
#pragma unroll
    for (int k = 0; k < 16; ++k) {
        if (bkt[k] >= 0) {
            int p = base_s[bkt[k]] + atomicAdd(&cur[bkt[k]], 1);
            if (p < CAP) rec_buf[(size_t)bkt[k] * CAP + p] = item[k];
        }
    }
}

// ---------------- per-bucket counting sort -> global CSR ----------------
__global__ __launch_bounds__(256) void sort_kernel(
    const int* __restrict__ bucket_count,
    const unsigned long long* __restrict__ rec_buf,
    unsigned int* __restrict__ edges_g, int* __restrict__ offsets)
{
    __shared__ unsigned int sorted[CAP];          // 27.6 KB
    __shared__ int cnts[NB];
    __shared__ int loc_off[NPB + 1];
    __shared__ int loc_cur[NPB];

    int b = blockIdx.x;
    int tid = threadIdx.x;
    int node_base = b * NPB;
    int n_nodes = min(NPB, N_NODES - node_base);

    cnts[tid] = min(bucket_count[tid], CAP);
    if (tid < NPB) loc_cur[tid] = 0;
    __syncthreads();

    __shared__ int ebase_s;
    if (tid == 0) {
        int r = 0;
        for (int i = 0; i < b; ++i) r += cnts[i];
        ebase_s = r;
    }
    __syncthreads();
    int ebase = ebase_s;
    int cnt = cnts[b];

    // pass 1: histogram by local target
    for (int i = tid; i < cnt; i += 256) {
        unsigned long long it = rec_buf[(size_t)b * CAP + i];
        atomicAdd(&loc_cur[(int)(it >> 32)], 1);
    }
    __syncthreads();
    if (tid == 0) {
        int r = 0;
        for (int n = 0; n < n_nodes; ++n) { loc_off[n] = r; r += loc_cur[n]; }
        loc_off[n_nodes] = r;
    }
    __syncthreads();
    if (tid < n_nodes) loc_cur[tid] = loc_off[tid];
    __syncthreads();

    // pass 2: place (rec_buf re-read is L2-hot)
    for (int i = tid; i < cnt; i += 256) {
        unsigned long long it = rec_buf[(size_t)b * CAP + i];
        int p = atomicAdd(&loc_cur[(int)(it >> 32)], 1);
        sorted[p] = (unsigned int)it;
    }
    __syncthreads();

    // coalesced CSR write + offsets
    for (int i = tid; i < cnt; i += 256) edges_g[ebase + i] = sorted[i];
    for (int n = tid; n < n_nodes; n += 256) offsets[node_base + n] = ebase + loc_off[n];
    if (b == NB - 1 && tid == 0) offsets[N_NODES] = ebase + cnt;
}

// ---------------- fence-free grid barrier ----------------
// All rates traffic bypasses L1/L2 (sc0 sc1 -> coherent point), so NO cache
// maintenance is needed here: pure counter sync, proven protocol from round 2
// with the two fences deleted. __syncthreads() before arrival drains every
// wave's outstanding (bypass) stores to the coherent point.
__device__ __forceinline__ void grid_barrier(unsigned int* cnt, unsigned int target) {
    __syncthreads();
    if (threadIdx.x == 0) {
        __hip_atomic_fetch_add(cnt, 1u, __ATOMIC_RELAXED, __HIP_MEMORY_SCOPE_AGENT);
        while (__hip_atomic_load(cnt, __ATOMIC_RELAXED, __HIP_MEMORY_SCOPE_AGENT) < target)
            __builtin_amdgcn_s_sleep(4);
    }
    __syncthreads();
}

// 4 L2-bypassing 16B gathers + completion wait, in ONE asm block: consumers
// are data-dependent on outputs, so no instruction can read them pre-wait
// (rule #18 safe); "=&v" early-clobber keeps outputs off the address regs.
__device__ __forceinline__ void gather4_bypass(
    const f32x4* p0, const f32x4* p1, const f32x4* p2, const f32x4* p3,
    f32x4& a0, f32x4& a1, f32x4& a2, f32x4& a3)
{
    asm volatile(
        "global_load_dwordx4 %0, %4, off sc0 sc1\n\t"
        "global_load_dwordx4 %1, %5, off sc0 sc1\n\t"
        "global_load_dwordx4 %2, %6, off sc0 sc1\n\t"
        "global_load_dwordx4 %3, %7, off sc0 sc1\n\t"
        "s_waitcnt vmcnt(0)"
        : "=&v"(a0), "=&v"(a1), "=&v"(a2), "=&v"(a3)
        : "v"(p0), "v"(p1), "v"(p2), "v"(p3)
        : "memory");
}

// ---------------- persistent all-steps kernel ----------------
// One cooperative launch runs all 50 steps. Each block owns 3-4 tiles of 32
// nodes; edges staged in LDS ONCE; v/alpha/bias/CSR ranges in registers.
// rates stores/loads bypass L1/L2 -> no stale copies -> fence-free barrier.
// Edge ordering, G=8 shuffle reduce, fp16 weights identical to the passing
// multi-launch kernel -> bit-identical numerics.

__device__ __forceinline__ float rec_w(unsigned int rec) {
    return __half2float(__ushort_as_half((unsigned short)(rec >> 16)));
}

__global__ __launch_bounds__(256, 2) void persist_kernel(
    float* rates_a, float* rates_b,                    // [N][4] each
    const float* __restrict__ bias, const float* __restrict__ time_const,
    const int* __restrict__ offsets, const unsigned int* __restrict__ edges,
    const float* __restrict__ x, float* __restrict__ out,
    unsigned int* __restrict__ bar)
{
    __shared__ unsigned int eL[LCAP];                  // 20 KB
    const int b    = blockIdx.x;
    const int tid  = threadIdx.x;
    const int lane = tid & (G - 1);
    const int grp  = tid / G;                          // 0..31 node-in-tile
    const int nslot = 3 + (b < (NTILES - 3 * NBLK));   // blocks 0..26 own 4 tiles

    int   lbeg_r[4], lend_r[4], node_r[4];
    float v_r[4], al_r[4], bi_r[4];
#pragma unroll
    for (int k = 0; k < 4; ++k) {
        lbeg_r[k] = 0; lend_r[k] = 0; node_r[k] = -1;
        v_r[k] = 0.f; al_r[k] = 0.f; bi_r[k] = 0.f;
    }

    // ---- staging: edges -> LDS, per-node state -> registers, rates(t=0) ----
    int lbase = 0;
#pragma unroll
    for (int k = 0; k < 4; ++k) {
        if (k < nslot) {
            const int tt    = b + k * NBLK;
            const int node0 = tt * 32;
            const int ncnt  = min(32, N_NODES - node0);
            const int gbeg  = offsets[node0];
            const int gend  = offsets[node0 + ncnt];
            int cnt = gend - gbeg;
            if (lbase + cnt > LCAP) cnt = LCAP - lbase;   // safety, never expected
            for (int i = tid; i < cnt; i += 256) eL[lbase + i] = edges[gbeg + i];
            if (grp < ncnt) {
                const int node = node0 + grp;
                node_r[k] = node;
                int ob = min(offsets[node] - gbeg, cnt);
                int oe = min(offsets[node + 1] - gbeg, cnt);
                lbeg_r[k] = lbase + ob;
                lend_r[k] = lbase + oe;
                const float bb = bias[node];
                bi_r[k] = bb;
                al_r[k] = DT / fmaxf(time_const[node], DT);
                v_r[k]  = bb;
                if (lane < 4)
                    __hip_atomic_store(&rates_a[node * 4 + lane], fmaxf(bb, 0.f),
                                       __ATOMIC_RELAXED, __HIP_MEMORY_SCOPE_SYSTEM);
            }
            lbase += cnt;
        }
    }
    grid_barrier(bar, NBLK);   // rates(t=0) at coherent point, visible device-wide

    const int TN = T_STEPS * N_NODES;
    for (int t = 0; t < T_STEPS; ++t) {
        const f32x4* rin  = (const f32x4*)((t & 1) ? rates_b : rates_a);
        float*       rout = (t & 1) ? rates_a : rates_b;

#pragma unroll
        for (int k = 0; k < 4; ++k) {
            if (k < nslot) {
                const int node = node_r[k];
                const int oi = lane * TN + t * N_NODES + node;
                float xv = 0.f;
                if (node >= 0 && lane < 4) xv = x[oi];   // issue early, hides under gathers

                f32x4 acc = {0.f, 0.f, 0.f, 0.f};
                const int end = lend_r[k];
                int i = lbeg_r[k] + lane;
                unsigned int r0 = (i          < end) ? eL[i]         : 0u;
                unsigned int r1 = (i + G      < end) ? eL[i + G]     : 0u;
                unsigned int r2 = (i + 2 * G  < end) ? eL[i + 2 * G] : 0u;
                unsigned int r3 = (i + 3 * G  < end) ? eL[i + 3 * G] : 0u;
                while (i < end) {
                    unsigned int n0 = (i + 4 * G < end) ? eL[i + 4 * G] : 0u;
                    unsigned int n1 = (i + 5 * G < end) ? eL[i + 5 * G] : 0u;
                    unsigned int n2 = (i + 6 * G < end) ? eL[i + 6 * G] : 0u;
                    unsigned int n3 = (i + 7 * G < end) ? eL[i + 7 * G] : 0u;
                    f32x4 a0, a1, a2, a3;
                    gather4_bypass(rin + (r0 & 0xFFFFu), rin + (r1 & 0xFFFFu),
                                   rin + (r2 & 0xFFFFu), rin + (r3 & 0xFFFFu),
                                   a0, a1, a2, a3);
                    float w0 = rec_w(r0), w1 = rec_w(r1), w2 = rec_w(r2), w3 = rec_w(r3);
                    acc.x = fmaf(a0.x, w0, acc.x); acc.y = fmaf(a0.y, w0, acc.y);
                    acc.z = fmaf(a0.z, w0, acc.z); acc.w = fmaf(a0.w, w0, acc.w);
                    acc.x = fmaf(a1.x, w1, acc.x); acc.y = fmaf(a1.y, w1, acc.y);
                    acc.z = fmaf(a1.z, w1, acc.z); acc.w = fmaf(a1.w, w1, acc.w);
                    acc.x = fmaf(a2.x, w2, acc.x); acc.y = fmaf(a2.y, w2, acc.y);
                    acc.z = fmaf(a2.z, w2, acc.z); acc.w = fmaf(a2.w, w2, acc.w);
                    acc.x = fmaf(a3.x, w3, acc.x); acc.y = fmaf(a3.y, w3, acc.y);
                    acc.z = fmaf(a3.z, w3, acc.z); acc.w = fmaf(a3.w, w3, acc.w);
                    r0 = n0; r1 = n1; r2 = n2; r3 = n3;
                    i += 4 * G;
                }

#pragma unroll
                for (int m = 1; m < G; m <<= 1) {
                    acc.x += __shfl_xor(acc.x, m, 64);
                    acc.y += __shfl_xor(acc.y, m, 64);
                    acc.z += __shfl_xor(acc.z, m, 64);
                    acc.w += __shfl_xor(acc.w, m, 64);
                }

                if (node >= 0 && lane < 4) {
                    float sum = (lane == 0) ? acc.x : (lane == 1) ? acc.y
                              : (lane == 2) ? acc.z : acc.w;
                    float vv = v_r[k];
                    float vn = vv + al_r[k] * (bi_r[k] + sum + xv - vv);
                    v_r[k] = vn;
                    float r = fmaxf(vn, 0.f);
                    __hip_atomic_store(&rout[node * 4 + lane], r,
                                       __ATOMIC_RELAXED, __HIP_MEMORY_SCOPE_SYSTEM);
                    out[oi] = r;
                }
            }
        }
        if (t < T_STEPS - 1) grid_barrier(bar, (unsigned int)NBLK * (t + 2));
    }
}

// ---------------- launch ----------------

extern "C" void kernel_launch(void* const* d_in, const int* in_sizes, int n_in,
                              void* d_out, int out_size, void* d_ws, size_t ws_size,
                              hipStream_t stream) {
    const float* x            = (const float*)d_in[0];
    const float* bias         = (const float*)d_in[1];
    const float* time_const   = (const float*)d_in[2];
    const float* sign         = (const float*)d_in[3];
    const float* syn_count    = (const float*)d_in[4];
    const float* syn_strength = (const float*)d_in[5];
    const int*   src_idx      = (const int*)d_in[6];
    const int*   tgt_idx      = (const int*)d_in[7];
    float* out = (float*)d_out;

    char* ws = (char*)d_ws;
    size_t off = 0;
    auto alloc = [&](size_t bytes) -> void* {
        void* p = ws + off;
        off = (off + bytes + 255) & ~(size_t)255;
        return p;
    };
    float* rates_a  = (float*)alloc((size_t)N_NODES * 16);
    float* rates_b  = (float*)alloc((size_t)N_NODES * 16);
    int*   offsets  = (int*)  alloc((size_t)(N_NODES + 1) * 4);
    int*   bucket_count = (int*)alloc((size_t)NB * 4);
    unsigned int* bar   = (unsigned int*)alloc(256);
    unsigned int* edges = (unsigned int*)alloc((size_t)N_EDGES * 4);
    unsigned long long* rec_buf =
        (unsigned long long*)alloc((size_t)NB * CAP * 8);   // 14.2 MB

    int nb_tiles = (N_EDGES + TILE - 1) / TILE;

    zero_kernel<<<1, 256, 0, stream>>>(bucket_count, bar);
    bucket_kernel<<<nb_tiles, 256, 0, stream>>>(src_idx, tgt_idx, sign, syn_count,
                                                syn_strength, bucket_count, rec_buf);
    sort_kernel<<<NB, 256, 0, stream>>>(bucket_count, rec_buf, edges, offsets);

    void* kargs[] = {
        (void*)&rates_a, (void*)&rates_b, (void*)&bias, (void*)&time_const,
        (void*)&offsets, (void*)&edges, (void*)&x, (void*)&out, (void*)&bar
    };
    hipLaunchCooperativeKernel((const void*)persist_kernel, dim3(NBLK), dim3(256),
                               kargs, 0, stream);
}

// Round 5
// 2002.290 us; speedup vs baseline: 1.8851x; 1.1039x over previous
//
#include <hip/hip_runtime.h>
#include <hip/hip_fp16.h>

#define N_NODES 50000
#define N_EDGES 1600000
#define T_STEPS 50
#define DT      0.02f
#define NB      256    // buckets
#define NPB     196    // nodes per bucket (196*256 >= 50000)
#define CAP     6912   // max edges per bucket (mean 6272, +8 sigma)
#define TILE    4096   // edges per bucket_kernel block
#define G       8      // lanes per node group in step phase
#define NBLK    512    // persistent blocks (2/CU, co-resident)
#define NTILES  1563   // ceil(50000 / 32) node tiles of 32
#define LCAP    5120   // LDS edge records per block (4 tiles mean 4096, +16 sigma)

// ---------------- setup ----------------

__global__ __launch_bounds__(256) void zero_kernel(int* __restrict__ bucket_count,
                                                   unsigned int* __restrict__ bar) {
    bucket_count[threadIdx.x] = 0;
    if (threadIdx.x < 64) bar[threadIdx.x] = 0u;
}

// ---------------- bucketing: staged, line-friendly appends ----------------
// u64 item: low 32 = record (src | fp16w<<16), high 32 = target-within-bucket
__global__ __launch_bounds__(256) void bucket_kernel(
    const int* __restrict__ src, const int* __restrict__ tgt,
    const float* __restrict__ sign, const float* __restrict__ syn_count,
    const float* __restrict__ syn_strength,
    int* __restrict__ bucket_count, unsigned long long* __restrict__ rec_buf)
{
    __shared__ int hist[NB], base_s[NB], cur[NB];
    int tid = threadIdx.x;
    hist[tid] = 0;
    __syncthreads();

    int e0 = blockIdx.x * TILE + tid;
    int bkt[16];
    unsigned long long item[16];
#pragma unroll
    for (int k = 0; k < 16; ++k) {
        int e = e0 + k * 256;
        if (e < N_EDGES) {
            int t = tgt[e];
            int b = t / NPB;
            int tl = t - b * NPB;
            float w = sign[e] * fmaxf(syn_count[e], 0.f) * fmaxf(syn_strength[e], 0.f);
            unsigned int rec = (unsigned int)src[e] |
                               ((unsigned int)__half_as_ushort(__float2half(w)) << 16);
            bkt[k] = b;
            item[k] = (unsigned long long)rec | ((unsigned long long)tl << 32);
            atomicAdd(&hist[b], 1);
        } else {
            bkt[k] = -1;
        }
    }
    __syncthreads();
    base_s[tid] = atomicAdd(&bucket_count[tid], hist[tid]);
    cur[tid] = 0;
    __syncthreads();
#pragma unroll
    for (int k = 0; k < 16; ++k) {
        if (bkt[k] >= 0) {
            int p = base_s[bkt[k]] + atomicAdd(&cur[bkt[k]], 1);
            if (p < CAP) rec_buf[(size_t)bkt[k] * CAP + p] = item[k];
        }
    }
}

// ---------------- per-bucket counting sort -> global CSR ----------------
__global__ __launch_bounds__(256) void sort_kernel(
    const int* __restrict__ bucket_count,
    const unsigned long long* __restrict__ rec_buf,
    unsigned int* __restrict__ edges_g, int* __restrict__ offsets)
{
    __shared__ unsigned int sorted[CAP];          // 27.6 KB
    __shared__ int cnts[NB];
    __shared__ int loc_off[NPB + 1];
    __shared__ int loc_cur[NPB];

    int b = blockIdx.x;
    int tid = threadIdx.x;
    int node_base = b * NPB;
    int n_nodes = min(NPB, N_NODES - node_base);

    cnts[tid] = min(bucket_count[tid], CAP);
    if (tid < NPB) loc_cur[tid] = 0;
    __syncthreads();

    __shared__ int ebase_s;
    if (tid == 0) {
        int r = 0;
        for (int i = 0; i < b; ++i) r += cnts[i];
        ebase_s = r;
    }
    __syncthreads();
    int ebase = ebase_s;
    int cnt = cnts[b];

    // pass 1: histogram by local target
    for (int i = tid; i < cnt; i += 256) {
        unsigned long long it = rec_buf[(size_t)b * CAP + i];
        atomicAdd(&loc_cur[(int)(it >> 32)], 1);
    }
    __syncthreads();
    if (tid == 0) {
        int r = 0;
        for (int n = 0; n < n_nodes; ++n) { loc_off[n] = r; r += loc_cur[n]; }
        loc_off[n_nodes] = r;
    }
    __syncthreads();
    if (tid < n_nodes) loc_cur[tid] = loc_off[tid];
    __syncthreads();

    // pass 2: place (rec_buf re-read is L2-hot)
    for (int i = tid; i < cnt; i += 256) {
        unsigned long long it = rec_buf[(size_t)b * CAP + i];
        int p = atomicAdd(&loc_cur[(int)(it >> 32)], 1);
        sorted[p] = (unsigned int)it;
    }
    __syncthreads();

    // coalesced CSR write + offsets
    for (int i = tid; i < cnt; i += 256) edges_g[ebase + i] = sorted[i];
    for (int n = tid; n < n_nodes; n += 256) offsets[node_base + n] = ebase + loc_off[n];
    if (b == NB - 1 && tid == 0) offsets[N_NODES] = ebase + cnt;
}

// ---------------- grid barrier: counter + acquire-invalidate ----------------
// All kernel STORES (rates, out) are L1/L2-bypassing -> L2 never holds dirty
// kernel data and all writes are at the coherent point when a wave passes
// __syncthreads() (compiler drains vmcnt(0) before s_barrier). So the barrier
// needs: relaxed arrival RMW, spin, then ONE acquire-agent fence per block
// (buffer_inv sc1: tag invalidate of stale L1/L2 rates lines; no data
// movement, no wbl2). Gathers afterwards are NORMAL CACHED loads: 94% L2-hit
// within a step (16x line reuse), which round 4 proved bypass loads can't do.
__device__ __forceinline__ void grid_barrier(unsigned int* cnt, unsigned int target) {
    __syncthreads();   // drains each wave's (bypass) stores: vmcnt(0) before s_barrier
    if (threadIdx.x == 0) {
        __hip_atomic_fetch_add(cnt, 1u, __ATOMIC_RELAXED, __HIP_MEMORY_SCOPE_AGENT);
        while (__hip_atomic_load(cnt, __ATOMIC_RELAXED, __HIP_MEMORY_SCOPE_AGENT) < target)
            __builtin_amdgcn_s_sleep(2);
        // discard stale L1+L2 lines (round 2's proven acquire path)
        __builtin_amdgcn_fence(__ATOMIC_ACQUIRE, "agent");
    }
    __syncthreads();
}

// ---------------- persistent all-steps kernel ----------------
// One cooperative launch runs all 50 steps. Each block owns 3-4 tiles of 32
// nodes; edges staged in LDS ONCE; v/alpha/bias/CSR ranges in registers.
// rates/out stores bypass L1/L2; rates gathers are cached; one acquire fence
// per block per step restores coherence. Edge ordering, G=8 shuffle reduce,
// fp16 weights identical to the passing kernels -> bit-identical numerics.

__device__ __forceinline__ float rec_w(unsigned int rec) {
    return __half2float(__ushort_as_half((unsigned short)(rec >> 16)));
}

__global__ __launch_bounds__(256, 2) void persist_kernel(
    float* rates_a, float* rates_b,                    // [N][4] each
    const float* __restrict__ bias, const float* __restrict__ time_const,
    const int* __restrict__ offsets, const unsigned int* __restrict__ edges,
    const float* __restrict__ x, float* __restrict__ out,
    unsigned int* __restrict__ bar)
{
    __shared__ unsigned int eL[LCAP];                  // 20 KB
    const int b    = blockIdx.x;
    const int tid  = threadIdx.x;
    const int lane = tid & (G - 1);
    const int grp  = tid / G;                          // 0..31 node-in-tile
    const int nslot = 3 + (b < (NTILES - 3 * NBLK));   // blocks 0..26 own 4 tiles

    int   lbeg_r[4], lend_r[4], node_r[4];
    float v_r[4], al_r[4], bi_r[4];
#pragma unroll
    for (int k = 0; k < 4; ++k) {
        lbeg_r[k] = 0; lend_r[k] = 0; node_r[k] = -1;
        v_r[k] = 0.f; al_r[k] = 0.f; bi_r[k] = 0.f;
    }

    // ---- staging: edges -> LDS, per-node state -> registers, rates(t=0) ----
    int lbase = 0;
#pragma unroll
    for (int k = 0; k < 4; ++k) {
        if (k < nslot) {
            const int tt    = b + k * NBLK;
            const int node0 = tt * 32;
            const int ncnt  = min(32, N_NODES - node0);
            const int gbeg  = offsets[node0];
            const int gend  = offsets[node0 + ncnt];
            int cnt = gend - gbeg;
            if (lbase + cnt > LCAP) cnt = LCAP - lbase;   // safety, never expected
            for (int i = tid; i < cnt; i += 256) eL[lbase + i] = edges[gbeg + i];
            if (grp < ncnt) {
                const int node = node0 + grp;
                node_r[k] = node;
                int ob = min(offsets[node] - gbeg, cnt);
                int oe = min(offsets[node + 1] - gbeg, cnt);
                lbeg_r[k] = lbase + ob;
                lend_r[k] = lbase + oe;
                const float bb = bias[node];
                bi_r[k] = bb;
                al_r[k] = DT / fmaxf(time_const[node], DT);
                v_r[k]  = bb;
                if (lane < 4)
                    __hip_atomic_store(&rates_a[node * 4 + lane], fmaxf(bb, 0.f),
                                       __ATOMIC_RELAXED, __HIP_MEMORY_SCOPE_SYSTEM);
            }
            lbase += cnt;
        }
    }
    grid_barrier(bar, NBLK);   // rates(t=0) at coherent point + caches clean

    const int TN = T_STEPS * N_NODES;
    for (int t = 0; t < T_STEPS; ++t) {
        const float4* __restrict__ rin = (const float4*)((t & 1) ? rates_b : rates_a);
        float* rout = (t & 1) ? rates_a : rates_b;

#pragma unroll
        for (int k = 0; k < 4; ++k) {
            if (k < nslot) {
                const int node = node_r[k];
                const int oi = lane * TN + t * N_NODES + node;
                float xv = 0.f;
                if (node >= 0 && lane < 4) xv = x[oi];   // issue early, hides under gathers

                float4 acc = make_float4(0.f, 0.f, 0.f, 0.f);
                const int end = lend_r[k];
                int i = lbeg_r[k] + lane;
                unsigned int r0 = (i          < end) ? eL[i]         : 0u;
                unsigned int r1 = (i + G      < end) ? eL[i + G]     : 0u;
                unsigned int r2 = (i + 2 * G  < end) ? eL[i + 2 * G] : 0u;
                unsigned int r3 = (i + 3 * G  < end) ? eL[i + 3 * G] : 0u;
                while (i < end) {
                    unsigned int n0 = (i + 4 * G < end) ? eL[i + 4 * G] : 0u;
                    unsigned int n1 = (i + 5 * G < end) ? eL[i + 5 * G] : 0u;
                    unsigned int n2 = (i + 6 * G < end) ? eL[i + 6 * G] : 0u;
                    unsigned int n3 = (i + 7 * G < end) ? eL[i + 7 * G] : 0u;
                    float4 a0 = rin[r0 & 0xFFFFu];
                    float4 a1 = rin[r1 & 0xFFFFu];
                    float4 a2 = rin[r2 & 0xFFFFu];
                    float4 a3 = rin[r3 & 0xFFFFu];
                    float w0 = rec_w(r0), w1 = rec_w(r1), w2 = rec_w(r2), w3 = rec_w(r3);
                    acc.x = fmaf(a0.x, w0, acc.x); acc.y = fmaf(a0.y, w0, acc.y);
                    acc.z = fmaf(a0.z, w0, acc.z); acc.w = fmaf(a0.w, w0, acc.w);
                    acc.x = fmaf(a1.x, w1, acc.x); acc.y = fmaf(a1.y, w1, acc.y);
                    acc.z = fmaf(a1.z, w1, acc.z); acc.w = fmaf(a1.w, w1, acc.w);
                    acc.x = fmaf(a2.x, w2, acc.x); acc.y = fmaf(a2.y, w2, acc.y);
                    acc.z = fmaf(a2.z, w2, acc.z); acc.w = fmaf(a2.w, w2, acc.w);
                    acc.x = fmaf(a3.x, w3, acc.x); acc.y = fmaf(a3.y, w3, acc.y);
                    acc.z = fmaf(a3.z, w3, acc.z); acc.w = fmaf(a3.w, w3, acc.w);
                    r0 = n0; r1 = n1; r2 = n2; r3 = n3;
                    i += 4 * G;
                }

#pragma unroll
                for (int m = 1; m < G; m <<= 1) {
                    acc.x += __shfl_xor(acc.x, m, 64);
                    acc.y += __shfl_xor(acc.y, m, 64);
                    acc.z += __shfl_xor(acc.z, m, 64);
                    acc.w += __shfl_xor(acc.w, m, 64);
                }

                if (node >= 0 && lane < 4) {
                    float sum = (lane == 0) ? acc.x : (lane == 1) ? acc.y
                              : (lane == 2) ? acc.z : acc.w;
                    float vv = v_r[k];
                    float vn = vv + al_r[k] * (bi_r[k] + sum + xv - vv);
                    v_r[k] = vn;
                    float r = fmaxf(vn, 0.f);
                    // bypass stores: L2 stays clean, writes land at coherent point
                    __hip_atomic_store(&rout[node * 4 + lane], r,
                                       __ATOMIC_RELAXED, __HIP_MEMORY_SCOPE_SYSTEM);
                    __hip_atomic_store(&out[oi], r,
                                       __ATOMIC_RELAXED, __HIP_MEMORY_SCOPE_SYSTEM);
                }
            }
        }
        if (t < T_STEPS - 1) grid_barrier(bar, (unsigned int)NBLK * (t + 2));
    }
}

// ---------------- launch ----------------

extern "C" void kernel_launch(void* const* d_in, const int* in_sizes, int n_in,
                              void* d_out, int out_size, void* d_ws, size_t ws_size,
                              hipStream_t stream) {
    const float* x            = (const float*)d_in[0];
    const float* bias         = (const float*)d_in[1];
    const float* time_const   = (const float*)d_in[2];
    const float* sign         = (const float*)d_in[3];
    const float* syn_count    = (const float*)d_in[4];
    const float* syn_strength = (const float*)d_in[5];
    const int*   src_idx      = (const int*)d_in[6];
    const int*   tgt_idx      = (const int*)d_in[7];
    float* out = (float*)d_out;

    char* ws = (char*)d_ws;
    size_t off = 0;
    auto alloc = [&](size_t bytes) -> void* {
        void* p = ws + off;
        off = (off + bytes + 255) & ~(size_t)255;
        return p;
    };
    float* rates_a  = (float*)alloc((size_t)N_NODES * 16);
    float* rates_b  = (float*)alloc((size_t)N_NODES * 16);
    int*   offsets  = (int*)  alloc((size_t)(N_NODES + 1) * 4);
    int*   bucket_count = (int*)alloc((size_t)NB * 4);
    unsigned int* bar   = (unsigned int*)alloc(256);
    unsigned int* edges = (unsigned int*)alloc((size_t)N_EDGES * 4);
    unsigned long long* rec_buf =
        (unsigned long long*)alloc((size_t)NB * CAP * 8);   // 14.2 MB

    int nb_tiles = (N_EDGES + TILE - 1) / TILE;

    zero_kernel<<<1, 256, 0, stream>>>(bucket_count, bar);
    bucket_kernel<<<nb_tiles, 256, 0, stream>>>(src_idx, tgt_idx, sign, syn_count,
                                                syn_strength, bucket_count, rec_buf);
    sort_kernel<<<NB, 256, 0, stream>>>(bucket_count, rec_buf, edges, offsets);

    void* kargs[] = {
        (void*)&rates_a, (void*)&rates_b, (void*)&bias, (void*)&time_const,
        (void*)&offsets, (void*)&edges, (void*)&x, (void*)&out, (void*)&bar
    };
    hipLaunchCooperativeKernel((const void*)persist_kernel, dim3(NBLK), dim3(256),
                               kargs, 0, stream);
}

// Round 6
// 1761.571 us; speedup vs baseline: 2.1427x; 1.1367x over previous
//
#include <hip/hip_runtime.h>
#include <hip/hip_fp16.h>

#define N_NODES 50000
#define N_EDGES 1600000
#define T_STEPS 50
#define DT      0.02f
#define NB      256    // buckets
#define NPB     196    // nodes per bucket (196*256 >= 50000)
#define CAP     6912   // max edges per bucket (mean 6272, +8 sigma)
#define TILE    4096   // edges per bucket_kernel block
#define G       8      // lanes per node group in step phase
#define NBLK    512    // persistent blocks (2/CU, co-resident)
#define NTILES  1563   // ceil(50000 / 32) node tiles of 32
#define LCAP    5120   // LDS edge records per block (4 tiles mean 4096, +16 sigma)
#define RSLOT   802816 // per-step rates buffer stride (N_NODES*16 -> 4KB-aligned)

// ---------------- setup ----------------

__global__ __launch_bounds__(256) void zero_kernel(int* __restrict__ bucket_count,
                                                   unsigned int* __restrict__ bar) {
    bucket_count[threadIdx.x] = 0;
    if (threadIdx.x < 64) bar[threadIdx.x] = 0u;
}

// ---------------- bucketing: staged, line-friendly appends ----------------
// u64 item: low 32 = record (src | fp16w<<16), high 32 = target-within-bucket
__global__ __launch_bounds__(256) void bucket_kernel(
    const int* __restrict__ src, const int* __restrict__ tgt,
    const float* __restrict__ sign, const float* __restrict__ syn_count,
    const float* __restrict__ syn_strength,
    int* __restrict__ bucket_count, unsigned long long* __restrict__ rec_buf)
{
    __shared__ int hist[NB], base_s[NB], cur[NB];
    int tid = threadIdx.x;
    hist[tid] = 0;
    __syncthreads();

    int e0 = blockIdx.x * TILE + tid;
    int bkt[16];
    unsigned long long item[16];
#pragma unroll
    for (int k = 0; k < 16; ++k) {
        int e = e0 + k * 256;
        if (e < N_EDGES) {
            int t = tgt[e];
            int b = t / NPB;
            int tl = t - b * NPB;
            float w = sign[e] * fmaxf(syn_count[e], 0.f) * fmaxf(syn_strength[e], 0.f);
            unsigned int rec = (unsigned int)src[e] |
                               ((unsigned int)__half_as_ushort(__float2half(w)) << 16);
            bkt[k] = b;
            item[k] = (unsigned long long)rec | ((unsigned long long)tl << 32);
            atomicAdd(&hist[b], 1);
        } else {
            bkt[k] = -1;
        }
    }
    __syncthreads();
    base_s[tid] = atomicAdd(&bucket_count[tid], hist[tid]);
    cur[tid] = 0;
    __syncthreads();
#pragma unroll
    for (int k = 0; k < 16; ++k) {
        if (bkt[k] >= 0) {
            int p = base_s[bkt[k]] + atomicAdd(&cur[bkt[k]], 1);
            if (p < CAP) rec_buf[(size_t)bkt[k] * CAP + p] = item[k];
        }
    }
}

// ---------------- per-bucket counting sort -> global CSR ----------------
__global__ __launch_bounds__(256) void sort_kernel(
    const int* __restrict__ bucket_count,
    const unsigned long long* __restrict__ rec_buf,
    unsigned int* __restrict__ edges_g, int* __restrict__ offsets)
{
    __shared__ unsigned int sorted[CAP];          // 27.6 KB
    __shared__ int cnts[NB];
    __shared__ int loc_off[NPB + 1];
    __shared__ int loc_cur[NPB];

    int b = blockIdx.x;
    int tid = threadIdx.x;
    int node_base = b * NPB;
    int n_nodes = min(NPB, N_NODES - node_base);

    cnts[tid] = min(bucket_count[tid], CAP);
    if (tid < NPB) loc_cur[tid] = 0;
    __syncthreads();

    __shared__ int ebase_s;
    if (tid == 0) {
        int r = 0;
        for (int i = 0; i < b; ++i) r += cnts[i];
        ebase_s = r;
    }
    __syncthreads();
    int ebase = ebase_s;
    int cnt = cnts[b];

    // pass 1: histogram by local target
    for (int i = tid; i < cnt; i += 256) {
        unsigned long long it = rec_buf[(size_t)b * CAP + i];
        atomicAdd(&loc_cur[(int)(it >> 32)], 1);
    }
    __syncthreads();
    if (tid == 0) {
        int r = 0;
        for (int n = 0; n < n_nodes; ++n) { loc_off[n] = r; r += loc_cur[n]; }
        loc_off[n_nodes] = r;
    }
    __syncthreads();
    if (tid < n_nodes) loc_cur[tid] = loc_off[tid];
    __syncthreads();

    // pass 2: place (rec_buf re-read is L2-hot)
    for (int i = tid; i < cnt; i += 256) {
        unsigned long long it = rec_buf[(size_t)b * CAP + i];
        int p = atomicAdd(&loc_cur[(int)(it >> 32)], 1);
        sorted[p] = (unsigned int)it;
    }
    __syncthreads();

    // coalesced CSR write + offsets
    for (int i = tid; i < cnt; i += 256) edges_g[ebase + i] = sorted[i];
    for (int n = tid; n < n_nodes; n += 256) offsets[node_base + n] = ebase + loc_off[n];
    if (b == NB - 1 && tid == 0) offsets[N_NODES] = ebase + cnt;
}

// ---------------- fence-free grid barrier (round-4 proven protocol) ----------
// No cache maintenance needed AT ALL: every step writes a FRESH buffer via
// L2-bypassing stores (L2 never dirty, data at coherent point when the wave
// passes __syncthreads' vmcnt(0) drain), and every step reads a buffer whose
// addresses were never cached before (virgin per dispatch) -> a cached read
// either misses (fetches fresh from L3) or hits a line filled AFTER the
// writes. Pure counter sync; no fences, no invalidates, no bypass reads.
__device__ __forceinline__ void grid_barrier(unsigned int* cnt, unsigned int target) {
    __syncthreads();
    if (threadIdx.x == 0) {
        __hip_atomic_fetch_add(cnt, 1u, __ATOMIC_RELAXED, __HIP_MEMORY_SCOPE_AGENT);
        while (__hip_atomic_load(cnt, __ATOMIC_RELAXED, __HIP_MEMORY_SCOPE_AGENT) < target)
            __builtin_amdgcn_s_sleep(2);
    }
    __syncthreads();
}

// ---------------- persistent all-steps kernel ----------------
// One cooperative launch runs all 50 steps. Each block owns 3-4 tiles of 32
// nodes; edges staged in LDS ONCE; v/alpha/bias/CSR ranges in registers.
// rates state ROTATES through 51 per-step buffers: writes bypass L1/L2,
// reads are normal cached loads of virgin addresses (full L2 aggregation,
// the thing rounds 2-5 lost). Edge ordering, G=8 shuffle reduce, fp16
// weights identical to the passing kernels -> bit-identical numerics.

__device__ __forceinline__ float rec_w(unsigned int rec) {
    return __half2float(__ushort_as_half((unsigned short)(rec >> 16)));
}

__global__ __launch_bounds__(256, 2) void persist_kernel(
    char* rates_base,                                  // 51 x RSLOT, [N][4] each
    const float* __restrict__ bias, const float* __restrict__ time_const,
    const int* __restrict__ offsets, const unsigned int* __restrict__ edges,
    const float* __restrict__ x, float* __restrict__ out,
    unsigned int* __restrict__ bar)
{
    __shared__ unsigned int eL[LCAP];                  // 20 KB
    const int b    = blockIdx.x;
    const int tid  = threadIdx.x;
    const int lane = tid & (G - 1);
    const int grp  = tid / G;                          // 0..31 node-in-tile
    const int nslot = 3 + (b < (NTILES - 3 * NBLK));   // blocks 0..26 own 4 tiles

    int   lbeg_r[4], lend_r[4], node_r[4];
    float v_r[4], al_r[4], bi_r[4];
#pragma unroll
    for (int k = 0; k < 4; ++k) {
        lbeg_r[k] = 0; lend_r[k] = 0; node_r[k] = -1;
        v_r[k] = 0.f; al_r[k] = 0.f; bi_r[k] = 0.f;
    }

    // ---- staging: edges -> LDS, per-node state -> registers, rates(t=0) ----
    int lbase = 0;
#pragma unroll
    for (int k = 0; k < 4; ++k) {
        if (k < nslot) {
            const int tt    = b + k * NBLK;
            const int node0 = tt * 32;
            const int ncnt  = min(32, N_NODES - node0);
            const int gbeg  = offsets[node0];
            const int gend  = offsets[node0 + ncnt];
            int cnt = gend - gbeg;
            if (lbase + cnt > LCAP) cnt = LCAP - lbase;   // safety, never expected
            for (int i = tid; i < cnt; i += 256) eL[lbase + i] = edges[gbeg + i];
            if (grp < ncnt) {
                const int node = node0 + grp;
                node_r[k] = node;
                int ob = min(offsets[node] - gbeg, cnt);
                int oe = min(offsets[node + 1] - gbeg, cnt);
                lbeg_r[k] = lbase + ob;
                lend_r[k] = lbase + oe;
                const float bb = bias[node];
                bi_r[k] = bb;
                al_r[k] = DT / fmaxf(time_const[node], DT);
                v_r[k]  = bb;
                if (lane < 4)
                    __hip_atomic_store((float*)rates_base + node * 4 + lane,
                                       fmaxf(bb, 0.f),
                                       __ATOMIC_RELAXED, __HIP_MEMORY_SCOPE_SYSTEM);
            }
            lbase += cnt;
        }
    }
    grid_barrier(bar, NBLK);   // rates(t=0) at coherent point

    const int TN = T_STEPS * N_NODES;
    for (int t = 0; t < T_STEPS; ++t) {
        const float4* __restrict__ rin = (const float4*)(rates_base + (size_t)t * RSLOT);
        float* rout = (float*)(rates_base + (size_t)(t + 1) * RSLOT);

#pragma unroll
        for (int k = 0; k < 4; ++k) {
            if (k < nslot) {
                const int node = node_r[k];
                const int oi = lane * TN + t * N_NODES + node;
                float xv = 0.f;
                if (node >= 0 && lane < 4) xv = x[oi];   // issue early, hides under gathers

                float4 acc = make_float4(0.f, 0.f, 0.f, 0.f);
                const int end = lend_r[k];
                int i = lbeg_r[k] + lane;
                unsigned int r0 = (i          < end) ? eL[i]         : 0u;
                unsigned int r1 = (i + G      < end) ? eL[i + G]     : 0u;
                unsigned int r2 = (i + 2 * G  < end) ? eL[i + 2 * G] : 0u;
                unsigned int r3 = (i + 3 * G  < end) ? eL[i + 3 * G] : 0u;
                while (i < end) {
                    unsigned int n0 = (i + 4 * G < end) ? eL[i + 4 * G] : 0u;
                    unsigned int n1 = (i + 5 * G < end) ? eL[i + 5 * G] : 0u;
                    unsigned int n2 = (i + 6 * G < end) ? eL[i + 6 * G] : 0u;
                    unsigned int n3 = (i + 7 * G < end) ? eL[i + 7 * G] : 0u;
                    float4 a0 = rin[r0 & 0xFFFFu];
                    float4 a1 = rin[r1 & 0xFFFFu];
                    float4 a2 = rin[r2 & 0xFFFFu];
                    float4 a3 = rin[r3 & 0xFFFFu];
                    float w0 = rec_w(r0), w1 = rec_w(r1), w2 = rec_w(r2), w3 = rec_w(r3);
                    acc.x = fmaf(a0.x, w0, acc.x); acc.y = fmaf(a0.y, w0, acc.y);
                    acc.z = fmaf(a0.z, w0, acc.z); acc.w = fmaf(a0.w, w0, acc.w);
                    acc.x = fmaf(a1.x, w1, acc.x); acc.y = fmaf(a1.y, w1, acc.y);
                    acc.z = fmaf(a1.z, w1, acc.z); acc.w = fmaf(a1.w, w1, acc.w);
                    acc.x = fmaf(a2.x, w2, acc.x); acc.y = fmaf(a2.y, w2, acc.y);
                    acc.z = fmaf(a2.z, w2, acc.z); acc.w = fmaf(a2.w, w2, acc.w);
                    acc.x = fmaf(a3.x, w3, acc.x); acc.y = fmaf(a3.y, w3, acc.y);
                    acc.z = fmaf(a3.z, w3, acc.z); acc.w = fmaf(a3.w, w3, acc.w);
                    r0 = n0; r1 = n1; r2 = n2; r3 = n3;
                    i += 4 * G;
                }

#pragma unroll
                for (int m = 1; m < G; m <<= 1) {
                    acc.x += __shfl_xor(acc.x, m, 64);
                    acc.y += __shfl_xor(acc.y, m, 64);
                    acc.z += __shfl_xor(acc.z, m, 64);
                    acc.w += __shfl_xor(acc.w, m, 64);
                }

                if (node >= 0 && lane < 4) {
                    float sum = (lane == 0) ? acc.x : (lane == 1) ? acc.y
                              : (lane == 2) ? acc.z : acc.w;
                    float vv = v_r[k];
                    float vn = vv + al_r[k] * (bi_r[k] + sum + xv - vv);
                    v_r[k] = vn;
                    float r = fmaxf(vn, 0.f);
                    // bypass stores: L2 stays clean, data lands at coherent point
                    __hip_atomic_store(&rout[node * 4 + lane], r,
                                       __ATOMIC_RELAXED, __HIP_MEMORY_SCOPE_SYSTEM);
                    __hip_atomic_store(&out[oi], r,
                                       __ATOMIC_RELAXED, __HIP_MEMORY_SCOPE_SYSTEM);
                }
            }
        }
        if (t < T_STEPS - 1) grid_barrier(bar, (unsigned int)NBLK * (t + 2));
    }
}

// ---------------- launch ----------------

extern "C" void kernel_launch(void* const* d_in, const int* in_sizes, int n_in,
                              void* d_out, int out_size, void* d_ws, size_t ws_size,
                              hipStream_t stream) {
    const float* x            = (const float*)d_in[0];
    const float* bias         = (const float*)d_in[1];
    const float* time_const   = (const float*)d_in[2];
    const float* sign         = (const float*)d_in[3];
    const float* syn_count    = (const float*)d_in[4];
    const float* syn_strength = (const float*)d_in[5];
    const int*   src_idx      = (const int*)d_in[6];
    const int*   tgt_idx      = (const int*)d_in[7];
    float* out = (float*)d_out;

    char* ws = (char*)d_ws;
    size_t off = 0;
    auto alloc = [&](size_t bytes) -> void* {
        void* p = ws + off;
        off = (off + bytes + 255) & ~(size_t)255;
        return p;
    };
    int*   offsets  = (int*)  alloc((size_t)(N_NODES + 1) * 4);
    int*   bucket_count = (int*)alloc((size_t)NB * 4);
    unsigned int* bar   = (unsigned int*)alloc(256);
    unsigned int* edges = (unsigned int*)alloc((size_t)N_EDGES * 4);
    unsigned long long* rec_buf =
        (unsigned long long*)alloc((size_t)NB * CAP * 8);   // 14.2 MB
    char* rates_base = (char*)alloc((size_t)(T_STEPS + 1) * RSLOT);  // 40.9 MB

    int nb_tiles = (N_EDGES + TILE - 1) / TILE;

    zero_kernel<<<1, 256, 0, stream>>>(bucket_count, bar);
    bucket_kernel<<<nb_tiles, 256, 0, stream>>>(src_idx, tgt_idx, sign, syn_count,
                                                syn_strength, bucket_count, rec_buf);
    sort_kernel<<<NB, 256, 0, stream>>>(bucket_count, rec_buf, edges, offsets);

    void* kargs[] = {
        (void*)&rates_base, (void*)&bias, (void*)&time_const,
        (void*)&offsets, (void*)&edges, (void*)&x, (void*)&out, (void*)&bar
    };
    hipLaunchCooperativeKernel((const void*)persist_kernel, dim3(NBLK), dim3(256),
                               kargs, 0, stream);
}

// Round 8
// 769.967 us; speedup vs baseline: 4.9023x; 2.2879x over previous
//
#include <hip/hip_runtime.h>
#include <hip/hip_fp16.h>

#define N_NODES 50000
#define N_EDGES 1600000
#define T_STEPS 50
#define DT      0.02f
#define NB      256    // buckets
#define NPB     196    // nodes per bucket (196*256 >= 50000)
#define CAP     6912   // max edges per bucket (mean 6272, +8 sigma)
#define TILE    4096   // edges per bucket_kernel block
#define G       8      // lanes per node group in step phase
#define NBLK    512    // persistent blocks (2/CU, co-resident)
#define NTILES  1563   // ceil(50000 / 32) node tiles of 32
#define LCAP    5120   // LDS edge records per block (4 tiles mean 4096, +16 sigma)
#define RSLOT   802816 // per-step rates buffer stride (N_NODES*16 -> 4KB-aligned)

// barrier layout in bar[]: bar[0] = release word; flag(i) = bar[64 + 4*i]
#define BAR_REL  0
#define BAR_ARR  64

// clang ext vector: lowers to a real 4-VGPR tuple for inline asm (float4 is a
// struct and fails with "indirect register inputs" -- round 7 lesson)
typedef __attribute__((ext_vector_type(4))) float f32x4;

// ---------------- setup ----------------

__global__ __launch_bounds__(256) void zero_kernel(int* __restrict__ bucket_count,
                                                   unsigned int* __restrict__ bar) {
    bucket_count[threadIdx.x] = 0;
    for (int i = threadIdx.x; i < 4096; i += 256) bar[i] = 0u;
}

// ---------------- bucketing: staged, line-friendly appends ----------------
// u64 item: low 32 = record (src | fp16w<<16), high 32 = target-within-bucket
__global__ __launch_bounds__(256) void bucket_kernel(
    const int* __restrict__ src, const int* __restrict__ tgt,
    const float* __restrict__ sign, const float* __restrict__ syn_count,
    const float* __restrict__ syn_strength,
    int* __restrict__ bucket_count, unsigned long long* __restrict__ rec_buf)
{
    __shared__ int hist[NB], base_s[NB], cur[NB];
    int tid = threadIdx.x;
    hist[tid] = 0;
    __syncthreads();

    int e0 = blockIdx.x * TILE + tid;
    int bkt[16];
    unsigned long long item[16];
#pragma unroll
    for (int k = 0; k < 16; ++k) {
        int e = e0 + k * 256;
        if (e < N_EDGES) {
            int t = tgt[e];
            int b = t / NPB;
            int tl = t - b * NPB;
            float w = sign[e] * fmaxf(syn_count[e], 0.f) * fmaxf(syn_strength[e], 0.f);
            unsigned int rec = (unsigned int)src[e] |
                               ((unsigned int)__half_as_ushort(__float2half(w)) << 16);
            bkt[k] = b;
            item[k] = (unsigned long long)rec | ((unsigned long long)tl << 32);
            atomicAdd(&hist[b], 1);
        } else {
            bkt[k] = -1;
        }
    }
    __syncthreads();
    base_s[tid] = atomicAdd(&bucket_count[tid], hist[tid]);
    cur[tid] = 0;
    __syncthreads();
#pragma unroll
    for (int k = 0; k < 16; ++k) {
        if (bkt[k] >= 0) {
            int p = base_s[bkt[k]] + atomicAdd(&cur[bkt[k]], 1);
            if (p < CAP) rec_buf[(size_t)bkt[k] * CAP + p] = item[k];
        }
    }
}

// ---------------- per-bucket counting sort -> global CSR ----------------
__global__ __launch_bounds__(256) void sort_kernel(
    const int* __restrict__ bucket_count,
    const unsigned long long* __restrict__ rec_buf,
    unsigned int* __restrict__ edges_g, int* __restrict__ offsets)
{
    __shared__ unsigned int sorted[CAP];          // 27.6 KB
    __shared__ int cnts[NB];
    __shared__ int loc_off[NPB + 1];
    __shared__ int loc_cur[NPB];

    int b = blockIdx.x;
    int tid = threadIdx.x;
    int node_base = b * NPB;
    int n_nodes = min(NPB, N_NODES - node_base);

    cnts[tid] = min(bucket_count[tid], CAP);
    if (tid < NPB) loc_cur[tid] = 0;
    __syncthreads();

    __shared__ int ebase_s;
    if (tid == 0) {
        int r = 0;
        for (int i = 0; i < b; ++i) r += cnts[i];
        ebase_s = r;
    }
    __syncthreads();
    int ebase = ebase_s;
    int cnt = cnts[b];

    // pass 1: histogram by local target
    for (int i = tid; i < cnt; i += 256) {
        unsigned long long it = rec_buf[(size_t)b * CAP + i];
        atomicAdd(&loc_cur[(int)(it >> 32)], 1);
    }
    __syncthreads();
    if (tid == 0) {
        int r = 0;
        for (int n = 0; n < n_nodes; ++n) { loc_off[n] = r; r += loc_cur[n]; }
        loc_off[n_nodes] = r;
    }
    __syncthreads();
    if (tid < n_nodes) loc_cur[tid] = loc_off[tid];
    __syncthreads();

    // pass 2: place (rec_buf re-read is L2-hot)
    for (int i = tid; i < cnt; i += 256) {
        unsigned long long it = rec_buf[(size_t)b * CAP + i];
        int p = atomicAdd(&loc_cur[(int)(it >> 32)], 1);
        sorted[p] = (unsigned int)it;
    }
    __syncthreads();

    // coalesced CSR write + offsets
    for (int i = tid; i < cnt; i += 256) edges_g[ebase + i] = sorted[i];
    for (int n = tid; n < n_nodes; n += 256) offsets[node_base + n] = ebase + loc_off[n];
    if (b == NB - 1 && tid == 0) offsets[N_NODES] = ebase + cnt;
}

// ---------------- contention-free grid barrier ----------------
// Correctness basis (rounds 4-6, all passed): rates writes bypass L1/L2 and
// are at the coherent point when a wave passes __syncthreads' vmcnt(0) drain;
// each step reads a VIRGIN buffer -> cached reads can never see stale data ->
// no fences/invalidates needed. This round removes the 512-way RMW contention:
// each block STORES its own arrival flag (no RMW); block 0's wave 0 scans all
// 512 flags in parallel (8/lane) and publishes one release word; spinners
// poll that single word with backoff.
__device__ __forceinline__ void grid_barrier(unsigned int* bar, unsigned int phase) {
    __syncthreads();   // drains vmcnt -> all bypass stores at coherent point
    if (blockIdx.x == 0) {
        int tid = threadIdx.x;
        if (tid < 64) {
            if (tid == 0)
                __hip_atomic_store(&bar[BAR_ARR + 0], phase,
                                   __ATOMIC_RELAXED, __HIP_MEMORY_SCOPE_AGENT);
            for (;;) {
                unsigned int mn = 0xFFFFFFFFu;
#pragma unroll
                for (int j = 0; j < 8; ++j) {
                    unsigned int v = __hip_atomic_load(&bar[BAR_ARR + 4 * (tid * 8 + j)],
                                                       __ATOMIC_RELAXED,
                                                       __HIP_MEMORY_SCOPE_AGENT);
                    mn = (v < mn) ? v : mn;
                }
                if (__all(mn >= phase)) break;
                __builtin_amdgcn_s_sleep(1);
            }
            if (tid == 0)
                __hip_atomic_store(&bar[BAR_REL], phase,
                                   __ATOMIC_RELAXED, __HIP_MEMORY_SCOPE_AGENT);
        }
        __syncthreads();
    } else {
        if (threadIdx.x == 0) {
            __hip_atomic_store(&bar[BAR_ARR + 4 * blockIdx.x], phase,
                               __ATOMIC_RELAXED, __HIP_MEMORY_SCOPE_AGENT);
            while (__hip_atomic_load(&bar[BAR_REL], __ATOMIC_RELAXED,
                                     __HIP_MEMORY_SCOPE_AGENT) < phase)
                __builtin_amdgcn_s_sleep(4);
        }
        __syncthreads();
    }
}

// one 16B L2-bypassing store (fire-and-forget; drained by __syncthreads).
// f32x4 (ext_vector_type) binds to a 4-VGPR tuple; float4 does not.
__device__ __forceinline__ void store16_bypass(float* p, f32x4 v) {
    asm volatile("global_store_dwordx4 %0, %1, off sc0 sc1"
                 :: "v"(p), "v"(v) : "memory");
}

// ---------------- persistent all-steps kernel ----------------
// One cooperative launch runs all 50 steps. Each block owns 3-4 tiles of 32
// nodes; edges staged in LDS ONCE; v/alpha/bias/CSR ranges in registers.
// rates rotate through 51 virgin per-step buffers: ONE dwordx4 bypass store
// per node (lane 0 holds all 4 batch sums after the xor-reduce), cached
// gathers, cached out stores. Arithmetic identical to the passing kernels
// -> bit-identical numerics.

__device__ __forceinline__ float rec_w(unsigned int rec) {
    return __half2float(__ushort_as_half((unsigned short)(rec >> 16)));
}

__global__ __launch_bounds__(256, 2) void persist_kernel(
    char* rates_base,                                  // 51 x RSLOT, [N][4] each
    const float* __restrict__ bias, const float* __restrict__ time_const,
    const int* __restrict__ offsets, const unsigned int* __restrict__ edges,
    const float* __restrict__ x, float* __restrict__ out,
    unsigned int* __restrict__ bar)
{
    __shared__ unsigned int eL[LCAP];                  // 20 KB
    const int b    = blockIdx.x;
    const int tid  = threadIdx.x;
    const int lane = tid & (G - 1);
    const int grp  = tid / G;                          // 0..31 node-in-tile
    const int nslot = 3 + (b < (NTILES - 3 * NBLK));   // blocks 0..26 own 4 tiles

    int    lbeg_r[4], lend_r[4], node_r[4];
    float4 v_r[4];
    float  al_r[4], bi_r[4];
#pragma unroll
    for (int k = 0; k < 4; ++k) {
        lbeg_r[k] = 0; lend_r[k] = 0; node_r[k] = -1;
        v_r[k] = make_float4(0.f, 0.f, 0.f, 0.f); al_r[k] = 0.f; bi_r[k] = 0.f;
    }

    // ---- staging: edges -> LDS, per-node state -> registers, rates(t=0) ----
    int lbase = 0;
#pragma unroll
    for (int k = 0; k < 4; ++k) {
        if (k < nslot) {
            const int tt    = b + k * NBLK;
            const int node0 = tt * 32;
            const int ncnt  = min(32, N_NODES - node0);
            const int gbeg  = offsets[node0];
            const int gend  = offsets[node0 + ncnt];
            int cnt = gend - gbeg;
            if (lbase + cnt > LCAP) cnt = LCAP - lbase;   // safety, never expected
            for (int i = tid; i < cnt; i += 256) eL[lbase + i] = edges[gbeg + i];
            if (grp < ncnt) {
                const int node = node0 + grp;
                node_r[k] = node;
                int ob = min(offsets[node] - gbeg, cnt);
                int oe = min(offsets[node + 1] - gbeg, cnt);
                lbeg_r[k] = lbase + ob;
                lend_r[k] = lbase + oe;
                const float bb = bias[node];
                bi_r[k] = bb;
                al_r[k] = DT / fmaxf(time_const[node], DT);
                v_r[k]  = make_float4(bb, bb, bb, bb);
                if (lane == 0) {
                    float r = fmaxf(bb, 0.f);
                    f32x4 rv = {r, r, r, r};
                    store16_bypass((float*)rates_base + node * 4, rv);
                }
            }
            lbase += cnt;
        }
    }
    grid_barrier(bar, 1u);   // rates(t=0) at coherent point

    const int TN = T_STEPS * N_NODES;
    for (int t = 0; t < T_STEPS; ++t) {
        const float4* __restrict__ rin = (const float4*)(rates_base + (size_t)t * RSLOT);
        float* rout = (float*)(rates_base + (size_t)(t + 1) * RSLOT);

#pragma unroll
        for (int k = 0; k < 4; ++k) {
            if (k < nslot) {
                const int node = node_r[k];
                // lane 0 carries all 4 batches; issue x loads early (hide under gathers)
                float xv0 = 0.f, xv1 = 0.f, xv2 = 0.f, xv3 = 0.f;
                if (node >= 0 && lane == 0) {
                    const float* xp = x + t * N_NODES + node;
                    xv0 = xp[0]; xv1 = xp[TN]; xv2 = xp[2 * TN]; xv3 = xp[3 * TN];
                }

                float4 acc = make_float4(0.f, 0.f, 0.f, 0.f);
                const int end = lend_r[k];
                int i = lbeg_r[k] + lane;
                unsigned int r0 = (i          < end) ? eL[i]         : 0u;
                unsigned int r1 = (i + G      < end) ? eL[i + G]     : 0u;
                unsigned int r2 = (i + 2 * G  < end) ? eL[i + 2 * G] : 0u;
                unsigned int r3 = (i + 3 * G  < end) ? eL[i + 3 * G] : 0u;
                while (i < end) {
                    unsigned int n0 = (i + 4 * G < end) ? eL[i + 4 * G] : 0u;
                    unsigned int n1 = (i + 5 * G < end) ? eL[i + 5 * G] : 0u;
                    unsigned int n2 = (i + 6 * G < end) ? eL[i + 6 * G] : 0u;
                    unsigned int n3 = (i + 7 * G < end) ? eL[i + 7 * G] : 0u;
                    float4 a0 = rin[r0 & 0xFFFFu];
                    float4 a1 = rin[r1 & 0xFFFFu];
                    float4 a2 = rin[r2 & 0xFFFFu];
                    float4 a3 = rin[r3 & 0xFFFFu];
                    float w0 = rec_w(r0), w1 = rec_w(r1), w2 = rec_w(r2), w3 = rec_w(r3);
                    acc.x = fmaf(a0.x, w0, acc.x); acc.y = fmaf(a0.y, w0, acc.y);
                    acc.z = fmaf(a0.z, w0, acc.z); acc.w = fmaf(a0.w, w0, acc.w);
                    acc.x = fmaf(a1.x, w1, acc.x); acc.y = fmaf(a1.y, w1, acc.y);
                    acc.z = fmaf(a1.z, w1, acc.z); acc.w = fmaf(a1.w, w1, acc.w);
                    acc.x = fmaf(a2.x, w2, acc.x); acc.y = fmaf(a2.y, w2, acc.y);
                    acc.z = fmaf(a2.z, w2, acc.z); acc.w = fmaf(a2.w, w2, acc.w);
                    acc.x = fmaf(a3.x, w3, acc.x); acc.y = fmaf(a3.y, w3, acc.y);
                    acc.z = fmaf(a3.z, w3, acc.z); acc.w = fmaf(a3.w, w3, acc.w);
                    r0 = n0; r1 = n1; r2 = n2; r3 = n3;
                    i += 4 * G;
                }

#pragma unroll
                for (int m = 1; m < G; m <<= 1) {
                    acc.x += __shfl_xor(acc.x, m, 64);
                    acc.y += __shfl_xor(acc.y, m, 64);
                    acc.z += __shfl_xor(acc.z, m, 64);
                    acc.w += __shfl_xor(acc.w, m, 64);
                }
                // after the reduce every lane holds all 4 batch sums

                if (node >= 0 && lane == 0) {
                    const float a  = al_r[k];
                    const float bb = bi_r[k];
                    float4 vv = v_r[k];
                    float4 vn;
                    vn.x = vv.x + a * (bb + acc.x + xv0 - vv.x);
                    vn.y = vv.y + a * (bb + acc.y + xv1 - vv.y);
                    vn.z = vv.z + a * (bb + acc.z + xv2 - vv.z);
                    vn.w = vv.w + a * (bb + acc.w + xv3 - vv.w);
                    v_r[k] = vn;
                    f32x4 rr = {fmaxf(vn.x, 0.f), fmaxf(vn.y, 0.f),
                                fmaxf(vn.z, 0.f), fmaxf(vn.w, 0.f)};
                    // ONE bypass dwordx4 per node (was 4 bypass dwords)
                    store16_bypass(&rout[node * 4], rr);
                    // out: plain cached stores (never re-read; flushed at kernel end)
                    float* op = out + t * N_NODES + node;
                    op[0]      = rr.x;
                    op[TN]     = rr.y;
                    op[2 * TN] = rr.z;
                    op[3 * TN] = rr.w;
                }
            }
        }
        if (t < T_STEPS - 1) grid_barrier(bar, (unsigned int)(t + 2));
    }
}

// ---------------- launch ----------------

extern "C" void kernel_launch(void* const* d_in, const int* in_sizes, int n_in,
                              void* d_out, int out_size, void* d_ws, size_t ws_size,
                              hipStream_t stream) {
    const float* x            = (const float*)d_in[0];
    const float* bias         = (const float*)d_in[1];
    const float* time_const   = (const float*)d_in[2];
    const float* sign         = (const float*)d_in[3];
    const float* syn_count    = (const float*)d_in[4];
    const float* syn_strength = (const float*)d_in[5];
    const int*   src_idx      = (const int*)d_in[6];
    const int*   tgt_idx      = (const int*)d_in[7];
    float* out = (float*)d_out;

    char* ws = (char*)d_ws;
    size_t off = 0;
    auto alloc = [&](size_t bytes) -> void* {
        void* p = ws + off;
        off = (off + bytes + 255) & ~(size_t)255;
        return p;
    };
    int*   offsets  = (int*)  alloc((size_t)(N_NODES + 1) * 4);
    int*   bucket_count = (int*)alloc((size_t)NB * 4);
    unsigned int* bar   = (unsigned int*)alloc(16384);
    unsigned int* edges = (unsigned int*)alloc((size_t)N_EDGES * 4);
    unsigned long long* rec_buf =
        (unsigned long long*)alloc((size_t)NB * CAP * 8);   // 14.2 MB
    char* rates_base = (char*)alloc((size_t)(T_STEPS + 1) * RSLOT);  // 40.9 MB

    int nb_tiles = (N_EDGES + TILE - 1) / TILE;

    zero_kernel<<<1, 256, 0, stream>>>(bucket_count, bar);
    bucket_kernel<<<nb_tiles, 256, 0, stream>>>(src_idx, tgt_idx, sign, syn_count,
                                                syn_strength, bucket_count, rec_buf);
    sort_kernel<<<NB, 256, 0, stream>>>(bucket_count, rec_buf, edges, offsets);

    void* kargs[] = {
        (void*)&rates_base, (void*)&bias, (void*)&time_const,
        (void*)&offsets, (void*)&edges, (void*)&x, (void*)&out, (void*)&bar
    };
    hipLaunchCooperativeKernel((const void*)persist_kernel, dim3(NBLK), dim3(256),
                               kargs, 0, stream);
}